// Round 5
// baseline (173.050 us; speedup 1.0000x reference)
//
#include <hip/hip_runtime.h>

#define NUM_B 8
#define NUM_C 64
#define NUM_O 64
#define DIM_H 256
#define DIM_W 256
#define SEG   8           // 8 output rows per block -> grid 256 = 1 block/CU, 16 waves
#define TPB   1024
#define XSS   72          // xs row stride in bf16 elems: 144 B

typedef __attribute__((ext_vector_type(8))) short bf16x8;
typedef __attribute__((ext_vector_type(4))) float f32x4;

__device__ __forceinline__ unsigned bf16r(float f) {   // RTNE fp32 -> bf16 bits
    unsigned u = __float_as_uint(f);
    return (u + 0x7fffu + ((u >> 16) & 1u)) >> 16;
}
__device__ __forceinline__ unsigned cvt_pk_bf16(float lo, float hi) {
    unsigned r;
    asm("v_cvt_pk_bf16_f32 %0, %1, %2" : "=v"(r) : "v"(lo), "v"(hi));
    return r;
}

__global__ __launch_bounds__(TPB, 4)   // 16 waves/CU -> <=128 unified regs/lane
void cpd_mfma(const float* __restrict__ x, const float* __restrict__ w1,
              const float* __restrict__ wh, const float* __restrict__ wv,
              const float* __restrict__ bias, float* __restrict__ out)
{
    // one x-row, transposed: xs[w+1][c] bf16; rows 0 and DIM_W+1 are zero pad for the w-shifts
    __shared__ unsigned short xs[DIM_W + 2][XSS];
    __shared__ float wvb[NUM_O][4];    // {wv0, wv1, wv2, bias} per o (epilogue coefs off-register)

    const int tid  = threadIdx.x;
    const int lane = tid & 63;
    const int wave = tid >> 6;         // [0,16)
    const int l15  = lane & 15;
    const int lhi  = lane >> 4;
    const int bx   = blockIdx.x;
    const int b    = bx >> 5;
    const int h0   = (bx & 31) * SEG;

    const int ot = wave & 3;           // o-tile: o = ot*16 ..
    const int wd = wave >> 2;          // w-quarter [0,4): w = wd*64 ..

    // ---- A fragments (regs): A_s[o][c] = wh[o][s] * w1[o][c]; slot: m=o=l15, k=c=kb*32+lhi*8+i
    bf16x8 afrag[3][2];
    {
        const int o = ot * 16 + l15;
        const float a0 = wh[o*3+0], a1 = wh[o*3+1], a2 = wh[o*3+2];
        #pragma unroll
        for (int kb = 0; kb < 2; ++kb) {
            const float* wr = w1 + o * NUM_C + kb * 32 + lhi * 8;
            const float4 wa = *(const float4*)wr;
            const float4 wb = *(const float4*)(wr + 4);
            const float w8[8] = {wa.x,wa.y,wa.z,wa.w,wb.x,wb.y,wb.z,wb.w};
            #pragma unroll
            for (int i = 0; i < 8; ++i) {
                afrag[0][kb][i] = (short)bf16r(a0 * w8[i]);
                afrag[1][kb][i] = (short)bf16r(a1 * w8[i]);
                afrag[2][kb][i] = (short)bf16r(a2 * w8[i]);
            }
        }
    }

    if (tid < XSS) { xs[0][tid] = 0; xs[DIM_W + 1][tid] = 0; }
    if (tid < NUM_O) {
        wvb[tid][0] = wv[tid*3+0];
        wvb[tid][1] = wv[tid*3+1];
        wvb[tid][2] = wv[tid*3+2];
        wvb[tid][3] = bias[tid];
    }

    // staging: thread owns w = tid&255, c-chunk ch (16 channels); 16 coalesced dword loads/row
    const int sw = tid & 255;
    const int ch = tid >> 8;           // [0,4)
    const float* xb = x + (size_t)b * NUM_C * DIM_H * DIM_W + sw;

    float xrA[16], xrB[16];            // two row banks: depth-2 prefetch
    if (h0 > 0) {                      // xrA <- row h0-1
        #pragma unroll
        for (int q = 0; q < 4; ++q)
            #pragma unroll
            for (int j = 0; j < 4; ++j)
                xrA[q*4+j] = xb[(size_t)(ch*16+q*4+j)*(DIM_H*DIM_W) + (size_t)(h0-1)*DIM_W];
    }
    #pragma unroll
    for (int q = 0; q < 4; ++q)        // xrB <- row h0
        #pragma unroll
        for (int j = 0; j < 4; ++j)
            xrB[q*4+j] = xb[(size_t)(ch*16+q*4+j)*(DIM_H*DIM_W) + (size_t)h0*DIM_W];

    f32x4 zP[4], zPP[4];
    #pragma unroll
    for (int t = 0; t < 4; ++t) { zP[t] = (f32x4){0,0,0,0}; zPP[t] = (f32x4){0,0,0,0}; }

    __syncthreads();

    // one STEP = one x-row: barrier(xs free) -> pack row h -> issue row h+2 -> barrier(xs ready)
    // -> GEMM -> store row h-1.  Round-3-verified sync structure; only tiling/prefetch changed.
#define STEP(HH, XR)                                                                      \
    do {                                                                                  \
        const int  h  = h0 + (HH);                                                        \
        const bool hv = (h >= 0) && (h < DIM_H);                                          \
        __builtin_amdgcn_s_barrier();                   /* xs free */                     \
        __builtin_amdgcn_sched_barrier(0);                                                \
        if (hv) {                                                                         \
            _Pragma("unroll")                                                             \
            for (int q = 0; q < 4; ++q) {                                                 \
                const unsigned lo = cvt_pk_bf16(XR[q*4+0], XR[q*4+1]);                    \
                const unsigned hi = cvt_pk_bf16(XR[q*4+2], XR[q*4+3]);                    \
                *(uint2*)&xs[sw + 1][ch * 16 + q * 4] = make_uint2(lo, hi);               \
            }                                                                             \
        }                                                                                 \
        if ((HH) <= SEG - 2 && h + 2 < DIM_H) {         /* refill freed bank: row h+2 */  \
            _Pragma("unroll")                                                             \
            for (int q = 0; q < 4; ++q)                                                   \
                _Pragma("unroll")                                                         \
                for (int j = 0; j < 4; ++j)                                               \
                    XR[q*4+j] = xb[(size_t)(ch*16+q*4+j)*(DIM_H*DIM_W)                    \
                                   + (size_t)(h+2)*DIM_W];                                \
        }                                                                                 \
        asm volatile("s_waitcnt lgkmcnt(0)" ::: "memory");                                \
        __builtin_amdgcn_s_barrier();                   /* xs ready (vmcnt in flight) */  \
        __builtin_amdgcn_sched_barrier(0);                                                \
        f32x4 acc[4];                                                                     \
        _Pragma("unroll")                                                                 \
        for (int t = 0; t < 4; ++t) acc[t] = (f32x4){0.f,0.f,0.f,0.f};                    \
        if (hv) {                                                                         \
            const int cb = lhi * 8;                                                       \
            _Pragma("unroll")                                                             \
            for (int t = 0; t < 4; ++t) {                                                 \
                const unsigned short* rp0 = &xs[wd*64 + t*16 + l15][cb];                  \
                _Pragma("unroll")                                                         \
                for (int s = 0; s < 3; ++s) {                                             \
                    const unsigned short* rp = rp0 + s * XSS;                             \
                    const bf16x8 b0 = *(const bf16x8*)rp;                                 \
                    const bf16x8 b1 = *(const bf16x8*)(rp + 32);                          \
                    acc[t] = __builtin_amdgcn_mfma_f32_16x16x32_bf16(afrag[s][0], b0, acc[t], 0,0,0); \
                    acc[t] = __builtin_amdgcn_mfma_f32_16x16x32_bf16(afrag[s][1], b1, acc[t], 0,0,0); \
                }                                                                         \
            }                                                                             \
        }                                                                                 \
        if ((HH) >= 1) {                                /* out row g = h-1 complete */    \
            const int g = h - 1;                                                          \
            _Pragma("unroll")                                                             \
            for (int r = 0; r < 4; ++r) {                                                 \
                const int o = ot * 16 + lhi * 4 + r;                                      \
                const float4 cf = *(const float4*)wvb[o];                                 \
                float* ob = out + ((size_t)(b * NUM_O + o) * DIM_H + g) * DIM_W           \
                                + wd * 64 + l15;                                          \
                _Pragma("unroll")                                                         \
                for (int t = 0; t < 4; ++t)                                               \
                    ob[t * 16] = cf.w + cf.x * zPP[t][r] + cf.y * zP[t][r]                \
                                      + cf.z * acc[t][r];                                 \
            }                                                                             \
        }                                                                                 \
        _Pragma("unroll")                                                                 \
        for (int t = 0; t < 4; ++t) { zPP[t] = zP[t]; zP[t] = acc[t]; }                   \
    } while (0)

    #pragma unroll
    for (int p = 0; p < (SEG + 2) / 2; ++p) {   // hh = -1..SEG; odd rows in xrA, even in xrB
        STEP(2 * p - 1, xrA);
        STEP(2 * p,     xrB);
    }
#undef STEP
}

extern "C" void kernel_launch(void* const* d_in, const int* in_sizes, int n_in,
                              void* d_out, int out_size, void* d_ws, size_t ws_size,
                              hipStream_t stream) {
    const float* x    = (const float*)d_in[0];
    const float* w1   = (const float*)d_in[1];
    const float* wh   = (const float*)d_in[2];
    const float* wv   = (const float*)d_in[3];
    const float* bias = (const float*)d_in[4];
    float* outp = (float*)d_out;
    cpd_mfma<<<dim3(NUM_B * (DIM_H / SEG)), dim3(TPB), 0, stream>>>(x, w1, wh, wv, bias, outp);
}

// Round 6
// 59.864 us; speedup vs baseline: 2.8907x; 2.8907x over previous
//
#include <hip/hip_runtime.h>

#define NUM_B 8
#define NUM_C 64
#define NUM_O 64
#define DIM_H 256
#define DIM_W 256
#define SEG   8           // 8 output rows per block
#define WT    128         // w-tile per block -> grid 512 = 2 blocks/CU
#define TPB   512
#define XSS   72          // xs row stride in bf16 elems: 144 B

typedef __attribute__((ext_vector_type(8))) short bf16x8;
typedef __attribute__((ext_vector_type(4))) float f32x4;

__device__ __forceinline__ unsigned bf16r(float f) {   // RTNE fp32 -> bf16 bits
    unsigned u = __float_as_uint(f);
    return (u + 0x7fffu + ((u >> 16) & 1u)) >> 16;
}
__device__ __forceinline__ unsigned cvt_pk_bf16(float lo, float hi) {
    unsigned r;
    asm("v_cvt_pk_bf16_f32 %0, %1, %2" : "=v"(r) : "v"(lo), "v"(hi));
    return r;
}

__global__ __launch_bounds__(TPB, 4)   // thin kernel: ~110 regs -> 16 waves/CU, 2 blocks
void cpd_mfma(const float* __restrict__ x, const float* __restrict__ w1,
              const float* __restrict__ wh, const float* __restrict__ wv,
              const float* __restrict__ bias, float* __restrict__ out)
{
    // one x-row slice, transposed: xs[wl+1][c] bf16; rows 0 and WT+1 hold halo (or zero at edges)
    __shared__ unsigned short xs[WT + 2][XSS];
    __shared__ float wvb[NUM_O][4];    // {wv0, wv1, wv2, bias} per o

    const int tid  = threadIdx.x;
    const int lane = tid & 63;
    const int wave = tid >> 6;         // [0,8)
    const int l15  = lane & 15;
    const int lhi  = lane >> 4;
    const int bx   = blockIdx.x;
    const int w0   = (bx & 1) * WT;
    const int h0   = ((bx >> 1) & 31) * SEG;
    const int b    = bx >> 6;

    const int ot = wave & 3;           // o-tile: o = ot*16 ..
    const int wq = wave >> 2;          // w-half of tile [0,2): wl = wq*64 ..

    // ---- A fragments (regs): A_s[o][c] = wh[o][s] * w1[o][c]; slot: m=o=l15, k=c=kb*32+lhi*8+i
    bf16x8 afrag[3][2];
    {
        const int o = ot * 16 + l15;
        const float a0 = wh[o*3+0], a1 = wh[o*3+1], a2 = wh[o*3+2];
        #pragma unroll
        for (int kb = 0; kb < 2; ++kb) {
            const float* wr = w1 + o * NUM_C + kb * 32 + lhi * 8;
            const float4 wa = *(const float4*)wr;
            const float4 wb = *(const float4*)(wr + 4);
            const float w8[8] = {wa.x,wa.y,wa.z,wa.w,wb.x,wb.y,wb.z,wb.w};
            #pragma unroll
            for (int i = 0; i < 8; ++i) {
                afrag[0][kb][i] = (short)bf16r(a0 * w8[i]);
                afrag[1][kb][i] = (short)bf16r(a1 * w8[i]);
                afrag[2][kb][i] = (short)bf16r(a2 * w8[i]);
            }
        }
    }

    if (tid < NUM_O) {
        wvb[tid][0] = wv[tid*3+0];
        wvb[tid][1] = wv[tid*3+1];
        wvb[tid][2] = wv[tid*3+2];
        wvb[tid][3] = bias[tid];
    }
    if (tid < XSS) { xs[0][tid] = 0; xs[WT + 1][tid] = 0; }

    // main staging: thread owns wl = tid&127, c-chunk ch (16 channels); 16 coalesced dwords/row
    const int sw = tid & (WT - 1);
    const int ch = tid >> 7;           // [0,4)
    const float* xb = x + (size_t)b * NUM_C * DIM_H * DIM_W + w0 + sw;

    // halo staging: threads 0..127 own (c = tid&63, side = tid>>6) -> columns w0-1 / w0+WT
    const int  hc     = tid & 63;
    const int  hside  = (tid >> 6) & 1;
    const int  hwg    = w0 - 1 + hside * (WT + 1);
    const bool hvalid = (tid < 128) && (hwg >= 0) && (hwg < DIM_W);
    const float* hb   = x + ((size_t)(b * NUM_C + hc) * DIM_H) * DIM_W + hwg;

    float xr[16];
    float hx = 0.f;
    if (h0 > 0) {                      // prologue: row h0-1
        #pragma unroll
        for (int q = 0; q < 4; ++q)
            #pragma unroll
            for (int j = 0; j < 4; ++j)
                xr[q*4+j] = xb[(size_t)(ch*16+q*4+j)*(DIM_H*DIM_W) + (size_t)(h0-1)*DIM_W];
        if (hvalid) hx = hb[(size_t)(h0-1)*DIM_W];
    }

    f32x4 zP[4], zPP[4];
    #pragma unroll
    for (int t = 0; t < 4; ++t) { zP[t] = (f32x4){0,0,0,0}; zPP[t] = (f32x4){0,0,0,0}; }

    __syncthreads();

    for (int hh = -1; hh <= SEG; ++hh) {
        const int  h  = h0 + hh;
        const bool hv = (h >= 0) && (h < DIM_H);

        __builtin_amdgcn_s_barrier();          // xs free (prev row fully consumed)
        __builtin_amdgcn_sched_barrier(0);

        if (hv) {
            // pack previously-loaded row into LDS (compiler inserts vmcnt waits on xr/hx use)
            #pragma unroll
            for (int q = 0; q < 4; ++q) {
                const unsigned lo = cvt_pk_bf16(xr[q*4+0], xr[q*4+1]);
                const unsigned hi = cvt_pk_bf16(xr[q*4+2], xr[q*4+3]);
                *(uint2*)&xs[sw + 1][ch * 16 + q * 4] = make_uint2(lo, hi);
            }
            if (tid < 128)
                xs[hside * (WT + 1)][hc] = (unsigned short)(hvalid ? bf16r(hx) : 0u);
        }
        // issue next row's loads; they stay in flight across the raw barriers
        if (hh < SEG && h + 1 < DIM_H) {
            #pragma unroll
            for (int q = 0; q < 4; ++q)
                #pragma unroll
                for (int j = 0; j < 4; ++j)
                    xr[q*4+j] = xb[(size_t)(ch*16+q*4+j)*(DIM_H*DIM_W) + (size_t)(h+1)*DIM_W];
            if (hvalid) hx = hb[(size_t)(h+1)*DIM_W];
        }

        asm volatile("s_waitcnt lgkmcnt(0)" ::: "memory");   // LDS writes visible
        __builtin_amdgcn_s_barrier();          // xs ready (vmcnt NOT drained)
        __builtin_amdgcn_sched_barrier(0);

        f32x4 acc[4];
        #pragma unroll
        for (int t = 0; t < 4; ++t) acc[t] = (f32x4){0.f,0.f,0.f,0.f};

        if (hv) {
            // z-row = sum_s A_s . X(wl + s - 1): horizontal conv folded into 3 shifted GEMMs
            const int cb = lhi * 8;
            #pragma unroll
            for (int t = 0; t < 4; ++t) {
                const unsigned short* rp0 = &xs[wq*64 + t*16 + l15][cb];
                #pragma unroll
                for (int s = 0; s < 3; ++s) {
                    const unsigned short* rp = rp0 + s * XSS;
                    const bf16x8 b0 = *(const bf16x8*)rp;          // c 0..31 slice
                    const bf16x8 b1 = *(const bf16x8*)(rp + 32);   // c 32..63 slice
                    acc[t] = __builtin_amdgcn_mfma_f32_16x16x32_bf16(afrag[s][0], b0, acc[t], 0,0,0);
                    acc[t] = __builtin_amdgcn_mfma_f32_16x16x32_bf16(afrag[s][1], b1, acc[t], 0,0,0);
                }
            }
        }

        // vertical 3x1 + bias: out row g = h-1 complete
        if (hh >= 1) {
            const int g = h - 1;
            #pragma unroll
            for (int r = 0; r < 4; ++r) {
                const int o = ot * 16 + lhi * 4 + r;
                const float4 cf = *(const float4*)wvb[o];
                float* ob = out + ((size_t)(b * NUM_O + o) * DIM_H + g) * DIM_W
                                + w0 + wq * 64 + l15;
                #pragma unroll
                for (int t = 0; t < 4; ++t)
                    ob[t * 16] = cf.w + cf.x * zPP[t][r] + cf.y * zP[t][r] + cf.z * acc[t][r];
            }
        }

        #pragma unroll
        for (int t = 0; t < 4; ++t) { zPP[t] = zP[t]; zP[t] = acc[t]; }
    }
}

extern "C" void kernel_launch(void* const* d_in, const int* in_sizes, int n_in,
                              void* d_out, int out_size, void* d_ws, size_t ws_size,
                              hipStream_t stream) {
    const float* x    = (const float*)d_in[0];
    const float* w1   = (const float*)d_in[1];
    const float* wh   = (const float*)d_in[2];
    const float* wv   = (const float*)d_in[3];
    const float* bias = (const float*)d_in[4];
    float* outp = (float*)d_out;
    cpd_mfma<<<dim3(NUM_B * 32 * 2), dim3(TPB), 0, stream>>>(x, w1, wh, wv, bias, outp);
}